// Round 2
// baseline (79.429 us; speedup 1.0000x reference)
//
#include <hip/hip_runtime.h>

// LIF spike scan: x[B=256, C=1024, T=128] f32 -> spikes same shape.
// Recurrence per (b,c) row over t:
//   mem = mem*TAU + x_t; spike = (mem > THRESH); mem -= spike*THRESH
// One thread per row; whole row (32 x float4 = 128 VGPRs) loaded up front so
// all 32 global loads are in flight simultaneously (single latency exposure).
// launch_bounds(256,2) -> VGPR cap 256, no spill risk for the 128-reg array.

#define TAU 0.5f
#define THRESH 0.5f

__global__ __launch_bounds__(256, 2) void lif_kernel(const float* __restrict__ x,
                                                     float* __restrict__ out) {
    const int row = blockIdx.x * blockDim.x + threadIdx.x;  // 0 .. 262143
    const long long base = (long long)row * 128;
    const float4* __restrict__ xin = reinterpret_cast<const float4*>(x + base);
    float4* __restrict__ o = reinterpret_cast<float4*>(out + base);

    float4 v[32];
#pragma unroll
    for (int j = 0; j < 32; ++j) v[j] = xin[j];   // 32 loads issued back-to-back

    float mem = 0.0f;
#pragma unroll
    for (int j = 0; j < 32; ++j) {
        float4 t = v[j];
        float4 s;
        mem = mem * TAU + t.x; s.x = (mem > THRESH) ? 1.0f : 0.0f; mem -= s.x * THRESH;
        mem = mem * TAU + t.y; s.y = (mem > THRESH) ? 1.0f : 0.0f; mem -= s.y * THRESH;
        mem = mem * TAU + t.z; s.z = (mem > THRESH) ? 1.0f : 0.0f; mem -= s.z * THRESH;
        mem = mem * TAU + t.w; s.w = (mem > THRESH) ? 1.0f : 0.0f; mem -= s.w * THRESH;
        o[j] = s;
    }
}

extern "C" void kernel_launch(void* const* d_in, const int* in_sizes, int n_in,
                              void* d_out, int out_size, void* d_ws, size_t ws_size,
                              hipStream_t stream) {
    const float* x = (const float*)d_in[0];
    float* out = (float*)d_out;
    const int rows = out_size / 128;  // B*C = 262144
    const int block = 256;
    const int grid = rows / block;    // 1024
    lif_kernel<<<grid, block, 0, stream>>>(x, out);
}

// Round 3
// 45.738 us; speedup vs baseline: 1.7366x; 1.7366x over previous
//
#include <hip/hip_runtime.h>

// LIF spike scan: x[B=256, C=1024, T=128] f32 -> spikes, same shape.
//   mem = mem*TAU + x_t; spike = (mem > THRESH); mem -= spike*THRESH
// Layout fix vs R1: per-thread rows caused 16B/lane @ 512B-stride global
// accesses (partial-line writebacks, ~1.9x write amplification). Now each
// block stages a [256 rows x 32 cols] tile through LDS so all global
// loads/stores are coalesced float4; each thread scans its own row in LDS.

#define TAU 0.5f
#define THRESH 0.5f
#define ROWS 256     // rows per block (= blockDim.x, one thread per row)
#define T 128
#define CHUNK 32     // time-columns staged per iteration
#define PADF 36      // LDS floats per row: 16B-aligned, min-round bank pattern

__global__ __launch_bounds__(256) void lif_kernel(const float* __restrict__ x,
                                                  float* __restrict__ out) {
    __shared__ float lds[ROWS * PADF];  // 36.9 KB -> 4 blocks/CU
    const int tid = threadIdx.x;
    const long long blockBase = (long long)blockIdx.x * ROWS * T;

    float mem = 0.0f;
    for (int c0 = 0; c0 < T; c0 += CHUNK) {
        // ---- stage: global -> LDS, coalesced (8 x float4 per thread) ----
#pragma unroll
        for (int t = 0; t < 8; ++t) {
            const int i = tid + t * 256;       // 0..2047 tile elements /4
            const int r = i >> 3;              // tile row
            const int c = (i & 7) << 2;        // float offset in chunk
            float4 v = *reinterpret_cast<const float4*>(
                x + blockBase + (long long)r * T + c0 + c);
            *reinterpret_cast<float4*>(&lds[r * PADF + c]) = v;
        }
        __syncthreads();

        // ---- compute: thread tid scans its own row's chunk ----
        float* myrow = &lds[tid * PADF];
#pragma unroll
        for (int j = 0; j < CHUNK / 4; ++j) {
            float4 v = *reinterpret_cast<float4*>(&myrow[j * 4]);
            float4 s;
            mem = mem * TAU + v.x; s.x = (mem > THRESH) ? 1.0f : 0.0f; mem -= s.x * THRESH;
            mem = mem * TAU + v.y; s.y = (mem > THRESH) ? 1.0f : 0.0f; mem -= s.y * THRESH;
            mem = mem * TAU + v.z; s.z = (mem > THRESH) ? 1.0f : 0.0f; mem -= s.z * THRESH;
            mem = mem * TAU + v.w; s.w = (mem > THRESH) ? 1.0f : 0.0f; mem -= s.w * THRESH;
            *reinterpret_cast<float4*>(&myrow[j * 4]) = s;
        }
        __syncthreads();

        // ---- store: LDS -> global, coalesced ----
#pragma unroll
        for (int t = 0; t < 8; ++t) {
            const int i = tid + t * 256;
            const int r = i >> 3;
            const int c = (i & 7) << 2;
            float4 s = *reinterpret_cast<float4*>(&lds[r * PADF + c]);
            *reinterpret_cast<float4*>(out + blockBase + (long long)r * T + c0 + c) = s;
        }
        __syncthreads();  // protect LDS from next chunk's staging
    }
}

extern "C" void kernel_launch(void* const* d_in, const int* in_sizes, int n_in,
                              void* d_out, int out_size, void* d_ws, size_t ws_size,
                              hipStream_t stream) {
    const float* x = (const float*)d_in[0];
    float* out = (float*)d_out;
    const int rows = out_size / T;        // 262144
    const int grid = rows / ROWS;         // 1024
    lif_kernel<<<grid, ROWS, 0, stream>>>(x, out);
}

// Round 5
// 45.131 us; speedup vs baseline: 1.7599x; 1.0134x over previous
//
#include <hip/hip_runtime.h>

// LIF spike scan: x[B=256, C=1024, T=128] f32 -> spikes, same shape.
//   mem = mem*TAU + x_t; spike = (mem > THRESH); mem -= spike*THRESH
// R4 = R3 with compile fix: __builtin_nontemporal_store requires a native
// clang vector type, not HIP's float4 class -> use ext_vector_type(4).
// Reads: direct global->regs per-thread row chunks (L1 absorbs the 512B
// stride scatter; FETCH-clean per R1). LDS only for store-side transpose so
// global stores are coalesced. NT stores keep the output stream from
// evicting the L3-resident input. 128-thread blocks -> 8 blocks/CU.

#define TAU 0.5f
#define THRESH 0.5f
#define T 128
#define ROWS 128     // rows per block = blockDim.x
#define CHUNK 32     // time-columns per iteration (4 iterations)
#define PADF 36      // LDS floats per row (16B-aligned pad, bank-spread)

typedef float floatx4 __attribute__((ext_vector_type(4)));

__global__ __launch_bounds__(128, 4) void lif_kernel(const float* __restrict__ x,
                                                     float* __restrict__ out) {
    __shared__ float lds[ROWS * PADF];  // 18.4 KB -> 8 blocks/CU
    const int tid = threadIdx.x;
    const long long blockBase = (long long)blockIdx.x * ROWS * T;
    const floatx4* __restrict__ xin4 =
        reinterpret_cast<const floatx4*>(x + blockBase + (long long)tid * T);

    float mem = 0.0f;
    floatx4 v[8];
#pragma unroll
    for (int j = 0; j < 8; ++j) v[j] = xin4[j];   // chunk 0

#pragma unroll
    for (int k = 0; k < 4; ++k) {
        const int c0 = k * CHUNK;

        // ---- compute scan on registers, spikes -> LDS row ----
#pragma unroll
        for (int j = 0; j < 8; ++j) {
            floatx4 t = v[j];
            floatx4 s;
            mem = mem * TAU + t.x; s.x = (mem > THRESH) ? 1.0f : 0.0f; mem -= s.x * THRESH;
            mem = mem * TAU + t.y; s.y = (mem > THRESH) ? 1.0f : 0.0f; mem -= s.y * THRESH;
            mem = mem * TAU + t.z; s.z = (mem > THRESH) ? 1.0f : 0.0f; mem -= s.z * THRESH;
            mem = mem * TAU + t.w; s.w = (mem > THRESH) ? 1.0f : 0.0f; mem -= s.w * THRESH;
            *reinterpret_cast<floatx4*>(&lds[tid * PADF + j * 4]) = s;
        }
        __syncthreads();

        // ---- prefetch next chunk (overlaps the store phase below) ----
        floatx4 nv[8];
        if (k < 3) {
#pragma unroll
            for (int j = 0; j < 8; ++j) nv[j] = xin4[(k + 1) * 8 + j];
        }

        // ---- coalesced non-temporal store: LDS -> global ----
#pragma unroll
        for (int t = 0; t < 8; ++t) {
            const int i = tid + t * ROWS;      // 0..1023 float4 slots
            const int r = i >> 3;              // tile row
            const int c = (i & 7) << 2;        // float col in chunk
            floatx4 s = *reinterpret_cast<floatx4*>(&lds[r * PADF + c]);
            __builtin_nontemporal_store(
                s, reinterpret_cast<floatx4*>(out + blockBase + (long long)r * T + c0 + c));
        }
        __syncthreads();

        if (k < 3) {
#pragma unroll
            for (int j = 0; j < 8; ++j) v[j] = nv[j];
        }
    }
}

extern "C" void kernel_launch(void* const* d_in, const int* in_sizes, int n_in,
                              void* d_out, int out_size, void* d_ws, size_t ws_size,
                              hipStream_t stream) {
    const float* x = (const float*)d_in[0];
    float* out = (float*)d_out;
    const int rows = out_size / T;        // 262144
    const int grid = rows / ROWS;         // 2048
    lif_kernel<<<grid, ROWS, 0, stream>>>(x, out);
}

// Round 7
// 44.587 us; speedup vs baseline: 1.7814x; 1.0122x over previous
//
#include <hip/hip_runtime.h>

// LIF spike scan: x[B=256, C=1024, T=128] f32 -> spikes, same shape.
//   mem = mem*TAU + x_t; spike = (mem > THRESH); mem -= spike*THRESH
// R5 (resubmit after infra failure): single-wave workgroups (ROWS=64) so
// barriers never cross-wave serialize; prefetch depth 2 (chunk k+2 issued at
// iter k) so each global load has ~2 iterations of latency cover.
// sched_barrier(0) pins the prefetch issue points (R1 showed the compiler
// otherwise sinks loads to their use). LDS only for the store-side
// transpose; NT coalesced stores. 4096 blocks = 16 single-wave blocks/CU;
// LDS 9.2KB*16 = 147KB/CU, fits.

#define TAU 0.5f
#define THRESH 0.5f
#define T 128
#define ROWS 64      // rows per block = blockDim.x (one wave)
#define CHUNK 32     // time-columns per iteration (4 iterations)
#define PADF 36      // LDS floats per row (16B-aligned pad, bank-spread)

typedef float floatx4 __attribute__((ext_vector_type(4)));

__global__ __launch_bounds__(64, 4) void lif_kernel(const float* __restrict__ x,
                                                    float* __restrict__ out) {
    __shared__ float lds[ROWS * PADF];  // 9.2 KB
    const int tid = threadIdx.x;
    const long long blockBase = (long long)blockIdx.x * ROWS * T;
    const floatx4* __restrict__ xin4 =
        reinterpret_cast<const floatx4*>(x + blockBase + (long long)tid * T);

    floatx4 v0[8], v1[8], v2[8];
#pragma unroll
    for (int j = 0; j < 8; ++j) v0[j] = xin4[j];        // chunk 0
#pragma unroll
    for (int j = 0; j < 8; ++j) v1[j] = xin4[8 + j];    // chunk 1
    __builtin_amdgcn_sched_barrier(0);  // keep preloads hoisted here

    float mem = 0.0f;
#pragma unroll
    for (int k = 0; k < 4; ++k) {
        const int c0 = k * CHUNK;

        // ---- compute scan on registers (chunk k), spikes -> LDS row ----
#pragma unroll
        for (int j = 0; j < 8; ++j) {
            floatx4 t = v0[j];
            floatx4 s;
            mem = mem * TAU + t.x; s.x = (mem > THRESH) ? 1.0f : 0.0f; mem -= s.x * THRESH;
            mem = mem * TAU + t.y; s.y = (mem > THRESH) ? 1.0f : 0.0f; mem -= s.y * THRESH;
            mem = mem * TAU + t.z; s.z = (mem > THRESH) ? 1.0f : 0.0f; mem -= s.z * THRESH;
            mem = mem * TAU + t.w; s.w = (mem > THRESH) ? 1.0f : 0.0f; mem -= s.w * THRESH;
            *reinterpret_cast<floatx4*>(&lds[tid * PADF + j * 4]) = s;
        }
        __syncthreads();

        // ---- issue prefetch of chunk k+2 (2 iterations of cover) ----
        if (k < 2) {
#pragma unroll
            for (int j = 0; j < 8; ++j) v2[j] = xin4[(k + 2) * 8 + j];
            __builtin_amdgcn_sched_barrier(0);  // pin issue before stores
        }

        // ---- coalesced non-temporal store: LDS -> global ----
#pragma unroll
        for (int t = 0; t < 8; ++t) {
            const int i = tid + t * ROWS;      // 0..511 float4 slots
            const int r = i >> 3;              // tile row (0..63)
            const int c = (i & 7) << 2;        // float col in chunk
            floatx4 s = *reinterpret_cast<floatx4*>(&lds[r * PADF + c]);
            __builtin_nontemporal_store(
                s, reinterpret_cast<floatx4*>(out + blockBase + (long long)r * T + c0 + c));
        }
        __syncthreads();

        // ---- rotate prefetch registers (static unroll -> renames) ----
        if (k < 3) {
#pragma unroll
            for (int j = 0; j < 8; ++j) v0[j] = v1[j];
        }
        if (k < 2) {
#pragma unroll
            for (int j = 0; j < 8; ++j) v1[j] = v2[j];
        }
    }
}

extern "C" void kernel_launch(void* const* d_in, const int* in_sizes, int n_in,
                              void* d_out, int out_size, void* d_ws, size_t ws_size,
                              hipStream_t stream) {
    const float* x = (const float*)d_in[0];
    float* out = (float*)d_out;
    const int rows = out_size / T;        // 262144
    const int grid = rows / ROWS;         // 4096
    lif_kernel<<<grid, ROWS, 0, stream>>>(x, out);
}